// Round 18
// baseline (103.347 us; speedup 1.0000x reference)
//
#include <hip/hip_runtime.h>
#include <hip/hip_bf16.h>

#define NB 256
#define NN 360
#define NF 360
#define NH 128
#define NKS 12   // 12 k-slices of 32 cover padded 384

using bf16x8 = __attribute__((ext_vector_type(8))) short;
using f32x4  = __attribute__((ext_vector_type(4))) float;

static __device__ __forceinline__ unsigned short f2bf(float f) {
  union { float f; unsigned u; } v; v.f = f;
  unsigned r = v.u + 0x7FFFu + ((v.u >> 16) & 1u);  // RNE
  return (unsigned short)(r >> 16);
}

// pack 8 f32 -> 8 bf16 via HW v_cvt_pk_bf16_f32 (compiler-generated, RNE)
static __device__ __forceinline__ bf16x8 pack8(float4 a, float4 b) {
  union { __hip_bfloat162 h[4]; bf16x8 v; } z;
  z.h[0] = __float22bfloat162_rn(make_float2(a.x, a.y));
  z.h[1] = __float22bfloat162_rn(make_float2(a.z, a.w));
  z.h[2] = __float22bfloat162_rn(make_float2(b.x, b.y));
  z.h[3] = __float22bfloat162_rn(make_float2(b.z, b.w));
  return z.v;
}

// chunk-linear tile offset: reader lane (lg*16+l15) gets chunk for (col n=ni*16+l15,
// k j=lg*8..+8) at ni*1024 + lane*16  (contiguous 1 KB/wave read, conflict-free)
static __device__ __forceinline__ int toff(int n, int j) {
  return ((n >> 4) << 10) + ((j >> 3) << 8) + ((n & 15) << 4) + ((j & 7) << 1);
}

// async global->LDS, 16B per lane: src per-lane, dst wave-uniform (HW adds lane*16)
static __device__ __forceinline__ void glds16(const void* src, void* dst) {
  __builtin_amdgcn_global_load_lds(
      (const __attribute__((address_space(1))) void*)src,
      (__attribute__((address_space(3))) void*)dst, 16, 0, 0);
}

// ---------------- K0: build chunk-linear kt-tiles of W1^T and W2^T ----------------------
__global__ void k_prep(const float* __restrict__ W1, const float* __restrict__ W2,
                       unsigned short* __restrict__ W1T, unsigned short* __restrict__ W2T) {
  const int t = blockIdx.x * 256 + threadIdx.x;     // 65536 = 12*4096 + 4*4096
  if (t < NKS * 4096) {
    const int ks = t >> 12, r = t & 4095;
    const int n = r >> 5, j = r & 31;
    const int k = ks * 32 + j;
    const float v = (k < NF) ? W1[k * NH + n] : 0.f;
    *(unsigned short*)((char*)W1T + ks * 8192 + toff(n, j)) = f2bf(v);
  } else {
    const int t2 = t - NKS * 4096;
    const int ks = t2 >> 12, r = t2 & 4095;
    const int n = r >> 5, j = r & 31;
    const int k = ks * 32 + j;
    *(unsigned short*)((char*)W2T + ks * 8192 + toff(n, j)) = f2bf(W2[k * NH + n]);
  }
}

// prefetch one slice (2 row-streams) into one NAMED float4 set
#define PF2(A0, B0, A1, B1, P0, P1, KK)      \
  {                                          \
    A0 = *(const float4*)((P0) + (KK));      \
    B0 = *(const float4*)((P0) + (KK) + 4);  \
    A1 = *(const float4*)((P1) + (KK));      \
    B1 = *(const float4*)((P1) + (KK) + 4);  \
  }

// t=1-only variant (phase C slices 0..4 have t=0 cached in regs)
#define PF1(A1, B1, P1, KK)                  \
  {                                          \
    A1 = *(const float4*)((P1) + (KK));      \
    B1 = *(const float4*)((P1) + (KK) + 4);  \
  }

// 3-deep rotation body: consume set (ks%3), reissue it for ks+3
#define ROT_BODY(P0, P1, LIM)                                              \
  const bool kv = (ks * 32 + kofs + 8) <= (LIM);                           \
  bf16x8 br0, br1;                                                         \
  {                                                                        \
    const int sel = ks % 3;                                                \
    if (sel == 0) {                                                        \
      br0 = kv ? pack8(ea0, eb0) : bz; br1 = kv ? pack8(ea1, eb1) : bz;    \
      if (ks + 3 < NKS) {                                                  \
        int kk = (ks + 3) * 32 + kofs; kk = kk < 352 ? kk : 352;           \
        PF2(ea0, eb0, ea1, eb1, P0, P1, kk);                               \
      }                                                                    \
    } else if (sel == 1) {                                                 \
      br0 = kv ? pack8(oa0, ob0) : bz; br1 = kv ? pack8(oa1, ob1) : bz;    \
      if (ks + 3 < NKS) {                                                  \
        int kk = (ks + 3) * 32 + kofs; kk = kk < 352 ? kk : 352;           \
        PF2(oa0, ob0, oa1, ob1, P0, P1, kk);                               \
      }                                                                    \
    } else {                                                               \
      br0 = kv ? pack8(pa0, pb0) : bz; br1 = kv ? pack8(pa1, pb1) : bz;    \
      if (ks + 3 < NKS) {                                                  \
        int kk = (ks + 3) * 32 + kofs; kk = kk < 352 ? kk : 352;           \
        PF2(pa0, pb0, pa1, pb1, P0, P1, kk);                               \
      }                                                                    \
    }                                                                      \
  }

// ---------------- fused per-batch kernel ------------------------------------------------
// LDS: panel 96 KB | ring (phase-A W1T, 6 tiles = 48 KB) aliasing h1s 52.2 KB | ghl 6 KB
// 1 block/CU, 12 waves (3/SIMD). Unified-file budget ~170 regs/wave:
// acc=64 AGPR + 84 VGPR = 148 -> ~22 regs slack -> t0-cache limited to 5 slices (20 regs).
__global__ __launch_bounds__(768)
__attribute__((amdgpu_waves_per_eu(3, 3))) void k_fused(
    const float* __restrict__ x, const float* __restrict__ adj,
    const unsigned short* __restrict__ W1T, const unsigned short* __restrict__ W2T,
    const float* __restrict__ b1, const float* __restrict__ b2,
    float* __restrict__ out, float* __restrict__ gh) {
  const int b = blockIdx.x;
  const int tid = threadIdx.x;
  const int wid = tid >> 6, lane = tid & 63, l15 = lane & 15, lg = lane >> 4;
  extern __shared__ char smem[];
  char* panel = smem;                                             // 98304 B
  char* ring = smem + 98304;                                      // 6x8KB W1T ring (A)
  unsigned short* h1s = (unsigned short*)(smem + 98304) + wid * 2176;  // B-epilogue
  float* ghl = (float*)(smem + 98304 + 52224);                    // [12][128]

  const int kofs = lg * 8;
  const f32x4 fz = {0.f, 0.f, 0.f, 0.f};
  const bf16x8 bz = {0, 0, 0, 0, 0, 0, 0, 0};

  f32x4 acc[2][8];
  float4 ea0, eb0, ea1, eb1, oa0, ob0, oa1, ob1, pa0, pb0, pa1, pb1;

  // =============== PHASE A: panel = (x@W1)^T (W1T via 6-tile LDS ring) ===============
  const int m0 = wid * 32 + l15, m1 = m0 + 16;
  const float* xr0 = x + ((size_t)b * NN + (m0 < NN ? m0 : NN - 1)) * NF;
  const float* xr1 = x + ((size_t)b * NN + (m1 < NN ? m1 : NN - 1)) * NF;
  const char* w1c = (const char*)W1T;

  // stage tiles 0..3 FIRST (so x-prefetches are newer on the in-order vmcnt stack)
  if (wid < 8) {
#pragma unroll
    for (int t = 0; t < 4; ++t)
      glds16(w1c + t * 8192 + wid * 1024 + (lane << 4), ring + t * 8192 + wid * 1024);
  }
  PF2(ea0, eb0, ea1, eb1, xr0, xr1, kofs);
  PF2(oa0, ob0, oa1, ob1, xr0, xr1, 32 + kofs);
  PF2(pa0, pb0, pa1, pb1, xr0, xr1, 64 + kofs);
#pragma unroll
  for (int i = 0; i < 2; ++i)
#pragma unroll
    for (int j = 0; j < 8; ++j) acc[i][j] = fz;

#pragma unroll
  for (int sk = 0; sk < 6; ++sk) {   // super-iter: 2 tiles per barrier
    // stager wait: tiles 2sk,2sk+1 resident (counted; never drains the x pipeline)
    if (wid < 8) {
      if (sk == 0)      asm volatile("s_waitcnt vmcnt(14)" ::: "memory");
      else if (sk < 5)  asm volatile("s_waitcnt vmcnt(10)" ::: "memory");
      else              asm volatile("s_waitcnt vmcnt(8)" ::: "memory");
    }
    __builtin_amdgcn_s_barrier();  // tiles 2sk,2sk+1 ready; slots (2sk-2..-1)%6 free
    if (sk < 4 && wid < 8) {
      const int t0s = 2 * sk + 4, t1s = 2 * sk + 5;
      glds16(w1c + t0s * 8192 + wid * 1024 + (lane << 4),
             ring + (t0s % 6) * 8192 + wid * 1024);
      glds16(w1c + t1s * 8192 + wid * 1024 + (lane << 4),
             ring + (t1s % 6) * 8192 + wid * 1024);
    }
#pragma unroll
    for (int ki = 0; ki < 2; ++ki) {
      const int ks = sk * 2 + ki;
      ROT_BODY(xr0, xr1, NF)
      __builtin_amdgcn_s_setprio(1);
#pragma unroll
      for (int hi = 0; hi < 8; ++hi) {
        bf16x8 af = *(const bf16x8*)(ring + (ks % 6) * 8192 + hi * 1024 + lane * 16);
        acc[0][hi] = __builtin_amdgcn_mfma_f32_16x16x32_bf16(af, br0, acc[0][hi], 0, 0, 0);
        acc[1][hi] = __builtin_amdgcn_mfma_f32_16x16x32_bf16(af, br1, acc[1][hi], 0, 0, 0);
      }
      __builtin_amdgcn_s_setprio(0);
    }
  }

  // panel1 write: value (h=hi*16+lg*4+r, m=wid*32+t*16+l15) -> tile wid, chunk-linear
  {
    char* pw = panel + wid * 8192 + (l15 >> 3) * 256 + (l15 & 7) * 2;
#pragma unroll
    for (int t = 0; t < 2; ++t) {
      const int m = wid * 32 + t * 16 + l15;
      const bool valid = m < NN;
#pragma unroll
      for (int hi = 0; hi < 8; ++hi)
#pragma unroll
        for (int r = 0; r < 4; ++r)
          *(unsigned short*)(pw + hi * 1024 + t * 512 + (lg * 4 + r) * 16) =
              valid ? f2bf(acc[t][hi][r]) : (unsigned short)0;
    }
  }

  // phase-B head-start: adj loads are barrier-independent; they land by barrier exit
  const float* ar0 = adj + ((size_t)b * NN + (m0 < NN ? m0 : NN - 1)) * NN;
  const float* ar1 = adj + ((size_t)b * NN + (m1 < NN ? m1 : NN - 1)) * NN;
  PF2(ea0, eb0, ea1, eb1, ar0, ar1, kofs);
  PF2(oa0, ob0, oa1, ob1, ar0, ar1, 32 + kofs);
  PF2(pa0, pb0, pa1, pb1, ar0, ar1, 64 + kofs);

  __syncthreads();  // #1: panel1 ready (also retires last ring reads)

  // =============== PHASE B: H1 = relu(adj@XW1+b1); H1W2 -> regs ===============
  // adj t=0 bf16 fragments of slices 0..4 retained in NAMED regs c0..c4 (20 regs)
  bf16x8 c0, c1, c2, c3, c4;
#pragma unroll
  for (int i = 0; i < 2; ++i)
#pragma unroll
    for (int j = 0; j < 8; ++j) acc[i][j] = fz;

#pragma unroll
  for (int ks = 0; ks < NKS; ++ks) {
    ROT_BODY(ar0, ar1, NN)
    if (ks == 0) c0 = br0;
    else if (ks == 1) c1 = br0;
    else if (ks == 2) c2 = br0;
    else if (ks == 3) c3 = br0;
    else if (ks == 4) c4 = br0;
    __builtin_amdgcn_s_setprio(1);
#pragma unroll
    for (int ni = 0; ni < 8; ++ni) {
      bf16x8 bfv = *(const bf16x8*)(panel + ks * 8192 + ni * 1024 + lane * 16);
      acc[0][ni] = __builtin_amdgcn_mfma_f32_16x16x32_bf16(br0, bfv, acc[0][ni], 0, 0, 0);
      acc[1][ni] = __builtin_amdgcn_mfma_f32_16x16x32_bf16(br1, bfv, acc[1][ni], 0, 0, 0);
    }
    __builtin_amdgcn_s_setprio(0);
  }

  // epilogue: bias+relu+mask, gh1 partials, per-wave transpose, GEMM2 -> packed ph
  float b1v[8];
#pragma unroll
  for (int ni = 0; ni < 8; ++ni) b1v[ni] = b1[ni * 16 + l15];
  float sgh[8];
#pragma unroll
  for (int ni = 0; ni < 8; ++ni) sgh[ni] = 0.f;
  unsigned ph[2][8][2];
#pragma unroll
  for (int t = 0; t < 2; ++t) {
#pragma unroll
    for (int ni = 0; ni < 8; ++ni) {
      const float bias = b1v[ni];
      float ssum = 0.f;
#pragma unroll
      for (int r = 0; r < 4; ++r) {
        const int orow = wid * 32 + t * 16 + lg * 4 + r;
        float h = acc[t][ni][r] + bias;
        h = h > 0.f ? h : 0.f;
        if (orow >= NN) h = 0.f;
        h1s[(lg * 4 + r) * 136 + ni * 16 + l15] = f2bf(h);
        ssum += h;
      }
      ssum += __shfl_xor(ssum, 16);
      ssum += __shfl_xor(ssum, 32);
      sgh[ni] += ssum;                               // meaningful on lg==0 lanes
    }
    f32x4 acc2[8];
#pragma unroll
    for (int j = 0; j < 8; ++j) acc2[j] = fz;
#pragma unroll
    for (int ks2 = 0; ks2 < 4; ++ks2) {
      bf16x8 a2 = *(const bf16x8*)&h1s[l15 * 136 + ks2 * 32 + lg * 8];
      __builtin_amdgcn_s_setprio(1);
#pragma unroll
      for (int ni = 0; ni < 8; ++ni) {
        bf16x8 b2f = *(const bf16x8*)(W2T + ks2 * 4096 + ni * 512 + lane * 8);
        acc2[ni] = __builtin_amdgcn_mfma_f32_16x16x32_bf16(a2, b2f, acc2[ni], 0, 0, 0);
      }
      __builtin_amdgcn_s_setprio(0);
    }
#pragma unroll
    for (int ni = 0; ni < 8; ++ni) {
      ph[t][ni][0] = (unsigned)f2bf(acc2[ni][0]) | ((unsigned)f2bf(acc2[ni][1]) << 16);
      ph[t][ni][1] = (unsigned)f2bf(acc2[ni][2]) | ((unsigned)f2bf(acc2[ni][3]) << 16);
    }
  }
  if (lg == 0) {
#pragma unroll
    for (int ni = 0; ni < 8; ++ni) ghl[wid * 128 + ni * 16 + l15] = sgh[ni];
  }
  __syncthreads();  // #2: panel1 fully consumed, ghl1 ready

  // phase-C head-start: t=1 streams only (t=0 of slices 0..2 comes from c0..c2)
  PF1(ea1, eb1, ar1, kofs);
  PF1(oa1, ob1, ar1, 32 + kofs);
  PF1(pa1, pb1, ar1, 64 + kofs);

  // panel2 overwrite: value (n=wid*32+t*16+lg*4+r, j=ni*16+l15), b64 packed (r=0..3)
  {
    char* pw2 = panel + wid * 8192 + (lg >> 1) * 256 + l15 * 16 + (lg & 1) * 8;
#pragma unroll
    for (int t = 0; t < 2; ++t)
#pragma unroll
      for (int ni = 0; ni < 8; ++ni)
        *(uint2*)(pw2 + ni * 1024 + t * 512) = make_uint2(ph[t][ni][0], ph[t][ni][1]);
  }
  if (tid < 128) {
    float s = 0.f;
#pragma unroll
    for (int w = 0; w < 12; ++w) s += ghl[w * 128 + tid];
    gh[b * 256 + tid] = s;
  }
  __syncthreads();  // #3: panel2 ready

  // =============== PHASE C: H2 = relu(adj@H1W2+b2) -> out; gh2 ===============
  // slices 0..4: t=0 operand from c0..c4 (no load, no pack); t=1 streamed.
#pragma unroll
  for (int i = 0; i < 2; ++i)
#pragma unroll
    for (int j = 0; j < 8; ++j) acc[i][j] = fz;

#pragma unroll
  for (int ks = 0; ks < NKS; ++ks) {
    const bool kv = (ks * 32 + kofs + 8) <= NN;
    const int sel = ks % 3;
    bf16x8 br0, br1;
    if (sel == 0)      br1 = kv ? pack8(ea1, eb1) : bz;
    else if (sel == 1) br1 = kv ? pack8(oa1, ob1) : bz;
    else               br1 = kv ? pack8(pa1, pb1) : bz;
    if (ks == 0)      br0 = c0;
    else if (ks == 1) br0 = c1;
    else if (ks == 2) br0 = c2;
    else if (ks == 3) br0 = c3;
    else if (ks == 4) br0 = c4;
    else if (sel == 0) br0 = kv ? pack8(ea0, eb0) : bz;
    else if (sel == 1) br0 = kv ? pack8(oa0, ob0) : bz;
    else               br0 = kv ? pack8(pa0, pb0) : bz;
    if (ks + 3 < NKS) {
      int kk = (ks + 3) * 32 + kofs; kk = kk < 352 ? kk : 352;
      if (sel == 0) {
        if (ks + 3 >= 5) { PF2(ea0, eb0, ea1, eb1, ar0, ar1, kk); }
        else             { PF1(ea1, eb1, ar1, kk); }
      } else if (sel == 1) {
        if (ks + 3 >= 5) { PF2(oa0, ob0, oa1, ob1, ar0, ar1, kk); }
        else             { PF1(oa1, ob1, ar1, kk); }
      } else {
        if (ks + 3 >= 5) { PF2(pa0, pb0, pa1, pb1, ar0, ar1, kk); }
        else             { PF1(pa1, pb1, ar1, kk); }
      }
    }
    __builtin_amdgcn_s_setprio(1);
#pragma unroll
    for (int ni = 0; ni < 8; ++ni) {
      bf16x8 bfv = *(const bf16x8*)(panel + ks * 8192 + ni * 1024 + lane * 16);
      acc[0][ni] = __builtin_amdgcn_mfma_f32_16x16x32_bf16(br0, bfv, acc[0][ni], 0, 0, 0);
      acc[1][ni] = __builtin_amdgcn_mfma_f32_16x16x32_bf16(br1, bfv, acc[1][ni], 0, 0, 0);
    }
    __builtin_amdgcn_s_setprio(0);
  }

  float b2v[8];
#pragma unroll
  for (int ni = 0; ni < 8; ++ni) b2v[ni] = b2[ni * 16 + l15];
  float* outb = out + (size_t)b * NN * NH;
#pragma unroll
  for (int ni = 0; ni < 8; ++ni) sgh[ni] = 0.f;
#pragma unroll
  for (int t = 0; t < 2; ++t) {
#pragma unroll
    for (int ni = 0; ni < 8; ++ni) {
      const float bias = b2v[ni];
      float ssum = 0.f;
#pragma unroll
      for (int r = 0; r < 4; ++r) {
        const int orow = wid * 32 + t * 16 + lg * 4 + r;
        float h = acc[t][ni][r] + bias;
        h = h > 0.f ? h : 0.f;
        if (orow < NN) {
          outb[orow * NH + ni * 16 + l15] = h;
          ssum += h;
        }
      }
      ssum += __shfl_xor(ssum, 16);
      ssum += __shfl_xor(ssum, 32);
      sgh[ni] += ssum;
    }
  }
  if (lg == 0) {
#pragma unroll
    for (int ni = 0; ni < 8; ++ni) ghl[wid * 128 + ni * 16 + l15] = sgh[ni];
  }
  __syncthreads();  // #4
  if (tid < 128) {
    float s = 0.f;
#pragma unroll
    for (int w = 0; w < 12; ++w) s += ghl[w * 128 + tid];
    gh[b * 256 + 128 + tid] = s;
  }
}

extern "C" void kernel_launch(void* const* d_in, const int* in_sizes, int n_in,
                              void* d_out, int out_size, void* d_ws, size_t ws_size,
                              hipStream_t stream) {
  const float* x   = (const float*)d_in[0];
  const float* adj = (const float*)d_in[1];
  const float* W1  = (const float*)d_in[2];
  const float* b1  = (const float*)d_in[3];
  const float* W2  = (const float*)d_in[4];
  const float* b2  = (const float*)d_in[5];
  float* out = (float*)d_out;                       // h2 [256,360,128] then gh [256,256]
  float* gh  = out + (size_t)NB * NN * NH;

  char* ws = (char*)d_ws;
  unsigned short* W1T = (unsigned short*)ws;                // 98,304 B
  unsigned short* W2T = (unsigned short*)(ws + 98304);      // 32,768 B

  const int smem_bytes = 98304 + 52224 + 6144;              // 156,672 B
  hipFuncSetAttribute((const void*)k_fused, hipFuncAttributeMaxDynamicSharedMemorySize,
                      smem_bytes);

  k_prep <<<256, 256, 0, stream>>>(W1, W2, W1T, W2T);
  k_fused<<<NB, 768, smem_bytes, stream>>>(x, adj, W1T, W2T, b1, b2, out, gh);
}

// Round 19
// 100.187 us; speedup vs baseline: 1.0315x; 1.0315x over previous
//
#include <hip/hip_runtime.h>
#include <hip/hip_bf16.h>

#define NB 256
#define NN 360
#define NF 360
#define NH 128
#define NKS 12   // 12 k-slices of 32 cover padded 384

using bf16x8 = __attribute__((ext_vector_type(8))) short;
using f32x4  = __attribute__((ext_vector_type(4))) float;

static __device__ __forceinline__ unsigned short f2bf(float f) {
  union { float f; unsigned u; } v; v.f = f;
  unsigned r = v.u + 0x7FFFu + ((v.u >> 16) & 1u);  // RNE
  return (unsigned short)(r >> 16);
}

// pack 8 f32 -> 8 bf16 via HW v_cvt_pk_bf16_f32 (compiler-generated, RNE)
static __device__ __forceinline__ bf16x8 pack8(float4 a, float4 b) {
  union { __hip_bfloat162 h[4]; bf16x8 v; } z;
  z.h[0] = __float22bfloat162_rn(make_float2(a.x, a.y));
  z.h[1] = __float22bfloat162_rn(make_float2(a.z, a.w));
  z.h[2] = __float22bfloat162_rn(make_float2(b.x, b.y));
  z.h[3] = __float22bfloat162_rn(make_float2(b.z, b.w));
  return z.v;
}

// chunk-linear tile offset: reader lane (lg*16+l15) gets chunk for (col n=ni*16+l15,
// k j=lg*8..+8) at ni*1024 + lane*16  (contiguous 1 KB/wave read, conflict-free)
static __device__ __forceinline__ int toff(int n, int j) {
  return ((n >> 4) << 10) + ((j >> 3) << 8) + ((n & 15) << 4) + ((j & 7) << 1);
}

// async global->LDS, 16B per lane: src per-lane, dst wave-uniform (HW adds lane*16)
static __device__ __forceinline__ void glds16(const void* src, void* dst) {
  __builtin_amdgcn_global_load_lds(
      (const __attribute__((address_space(1))) void*)src,
      (__attribute__((address_space(3))) void*)dst, 16, 0, 0);
}

// ---------------- K0: build chunk-linear kt-tiles of W1^T and W2^T ----------------------
__global__ void k_prep(const float* __restrict__ W1, const float* __restrict__ W2,
                       unsigned short* __restrict__ W1T, unsigned short* __restrict__ W2T) {
  const int t = blockIdx.x * 256 + threadIdx.x;     // 65536 = 12*4096 + 4*4096
  if (t < NKS * 4096) {
    const int ks = t >> 12, r = t & 4095;
    const int n = r >> 5, j = r & 31;
    const int k = ks * 32 + j;
    const float v = (k < NF) ? W1[k * NH + n] : 0.f;
    *(unsigned short*)((char*)W1T + ks * 8192 + toff(n, j)) = f2bf(v);
  } else {
    const int t2 = t - NKS * 4096;
    const int ks = t2 >> 12, r = t2 & 4095;
    const int n = r >> 5, j = r & 31;
    const int k = ks * 32 + j;
    *(unsigned short*)((char*)W2T + ks * 8192 + toff(n, j)) = f2bf(W2[k * NH + n]);
  }
}

// prefetch one slice (2 row-streams) into one NAMED float4 set
#define PF2(A0, B0, A1, B1, P0, P1, KK)      \
  {                                          \
    A0 = *(const float4*)((P0) + (KK));      \
    B0 = *(const float4*)((P0) + (KK) + 4);  \
    A1 = *(const float4*)((P1) + (KK));      \
    B1 = *(const float4*)((P1) + (KK) + 4);  \
  }

// 3-deep rotation body: consume set (ks%3), reissue it for ks+3
#define ROT_BODY(P0, P1, LIM)                                              \
  const bool kv = (ks * 32 + kofs + 8) <= (LIM);                           \
  bf16x8 br0, br1;                                                         \
  {                                                                        \
    const int sel = ks % 3;                                                \
    if (sel == 0) {                                                        \
      br0 = kv ? pack8(ea0, eb0) : bz; br1 = kv ? pack8(ea1, eb1) : bz;    \
      if (ks + 3 < NKS) {                                                  \
        int kk = (ks + 3) * 32 + kofs; kk = kk < 352 ? kk : 352;           \
        PF2(ea0, eb0, ea1, eb1, P0, P1, kk);                               \
      }                                                                    \
    } else if (sel == 1) {                                                 \
      br0 = kv ? pack8(oa0, ob0) : bz; br1 = kv ? pack8(oa1, ob1) : bz;    \
      if (ks + 3 < NKS) {                                                  \
        int kk = (ks + 3) * 32 + kofs; kk = kk < 352 ? kk : 352;           \
        PF2(oa0, ob0, oa1, ob1, P0, P1, kk);                               \
      }                                                                    \
    } else {                                                               \
      br0 = kv ? pack8(pa0, pb0) : bz; br1 = kv ? pack8(pa1, pb1) : bz;    \
      if (ks + 3 < NKS) {                                                  \
        int kk = (ks + 3) * 32 + kofs; kk = kk < 352 ? kk : 352;           \
        PF2(pa0, pb0, pa1, pb1, P0, P1, kk);                               \
      }                                                                    \
    }                                                                      \
  }

// ---------------- fused per-batch kernel ------------------------------------------------
// LDS: panel 96 KB | ring (phase-A W1T, 6 tiles = 48 KB) aliasing h1s 52.2 KB | ghl 6 KB
// 1 block/CU, 12 waves (3/SIMD). Unified-file budget ~170 regs/wave (acc=64 AGPR + ~84 V).
__global__ __launch_bounds__(768)
__attribute__((amdgpu_waves_per_eu(3, 3))) void k_fused(
    const float* __restrict__ x, const float* __restrict__ adj,
    const unsigned short* __restrict__ W1T, const unsigned short* __restrict__ W2T,
    const float* __restrict__ b1, const float* __restrict__ b2,
    float* __restrict__ out, float* __restrict__ gh) {
  const int b = blockIdx.x;
  const int tid = threadIdx.x;
  const int wid = tid >> 6, lane = tid & 63, l15 = lane & 15, lg = lane >> 4;
  extern __shared__ char smem[];
  char* panel = smem;                                             // 98304 B
  char* ring = smem + 98304;                                      // 6x8KB W1T ring (A)
  unsigned short* h1s = (unsigned short*)(smem + 98304) + wid * 2176;  // B-epilogue
  float* ghl = (float*)(smem + 98304 + 52224);                    // [12][128]

  const int kofs = lg * 8;
  const f32x4 fz = {0.f, 0.f, 0.f, 0.f};
  const bf16x8 bz = {0, 0, 0, 0, 0, 0, 0, 0};

  f32x4 acc[2][8];
  float4 ea0, eb0, ea1, eb1, oa0, ob0, oa1, ob1, pa0, pb0, pa1, pb1;

  // =============== PHASE A: panel = (x@W1)^T (W1T via 6-tile LDS ring) ===============
  const int m0 = wid * 32 + l15, m1 = m0 + 16;
  const float* xr0 = x + ((size_t)b * NN + (m0 < NN ? m0 : NN - 1)) * NF;
  const float* xr1 = x + ((size_t)b * NN + (m1 < NN ? m1 : NN - 1)) * NF;
  const char* w1c = (const char*)W1T;

  // stage tiles 0..3 FIRST (so x-prefetches are newer on the in-order vmcnt stack)
  if (wid < 8) {
#pragma unroll
    for (int t = 0; t < 4; ++t)
      glds16(w1c + t * 8192 + wid * 1024 + (lane << 4), ring + t * 8192 + wid * 1024);
  }
  PF2(ea0, eb0, ea1, eb1, xr0, xr1, kofs);
  PF2(oa0, ob0, oa1, ob1, xr0, xr1, 32 + kofs);
  PF2(pa0, pb0, pa1, pb1, xr0, xr1, 64 + kofs);
#pragma unroll
  for (int i = 0; i < 2; ++i)
#pragma unroll
    for (int j = 0; j < 8; ++j) acc[i][j] = fz;

#pragma unroll
  for (int sk = 0; sk < 6; ++sk) {   // super-iter: 2 tiles per barrier
    // stager wait: tiles 2sk,2sk+1 resident (counted; never drains the x pipeline)
    if (wid < 8) {
      if (sk == 0)      asm volatile("s_waitcnt vmcnt(14)" ::: "memory");
      else if (sk < 5)  asm volatile("s_waitcnt vmcnt(10)" ::: "memory");
      else              asm volatile("s_waitcnt vmcnt(8)" ::: "memory");
    }
    __builtin_amdgcn_s_barrier();  // tiles 2sk,2sk+1 ready; slots (2sk-2..-1)%6 free
    if (sk < 4 && wid < 8) {
      const int t0s = 2 * sk + 4, t1s = 2 * sk + 5;
      glds16(w1c + t0s * 8192 + wid * 1024 + (lane << 4),
             ring + (t0s % 6) * 8192 + wid * 1024);
      glds16(w1c + t1s * 8192 + wid * 1024 + (lane << 4),
             ring + (t1s % 6) * 8192 + wid * 1024);
    }
#pragma unroll
    for (int ki = 0; ki < 2; ++ki) {
      const int ks = sk * 2 + ki;
      ROT_BODY(xr0, xr1, NF)
      __builtin_amdgcn_s_setprio(1);
#pragma unroll
      for (int hi = 0; hi < 8; ++hi) {
        bf16x8 af = *(const bf16x8*)(ring + (ks % 6) * 8192 + hi * 1024 + lane * 16);
        acc[0][hi] = __builtin_amdgcn_mfma_f32_16x16x32_bf16(af, br0, acc[0][hi], 0, 0, 0);
        acc[1][hi] = __builtin_amdgcn_mfma_f32_16x16x32_bf16(af, br1, acc[1][hi], 0, 0, 0);
      }
      __builtin_amdgcn_s_setprio(0);
    }
  }

  // panel1 write: value (h=hi*16+lg*4+r, m=wid*32+t*16+l15) -> tile wid, chunk-linear
  {
    char* pw = panel + wid * 8192 + (l15 >> 3) * 256 + (l15 & 7) * 2;
#pragma unroll
    for (int t = 0; t < 2; ++t) {
      const int m = wid * 32 + t * 16 + l15;
      const bool valid = m < NN;
#pragma unroll
      for (int hi = 0; hi < 8; ++hi)
#pragma unroll
        for (int r = 0; r < 4; ++r)
          *(unsigned short*)(pw + hi * 1024 + t * 512 + (lg * 4 + r) * 16) =
              valid ? f2bf(acc[t][hi][r]) : (unsigned short)0;
    }
  }

  // phase-B head-start: adj loads are barrier-independent; they land by barrier exit
  const float* ar0 = adj + ((size_t)b * NN + (m0 < NN ? m0 : NN - 1)) * NN;
  const float* ar1 = adj + ((size_t)b * NN + (m1 < NN ? m1 : NN - 1)) * NN;
  PF2(ea0, eb0, ea1, eb1, ar0, ar1, kofs);
  PF2(oa0, ob0, oa1, ob1, ar0, ar1, 32 + kofs);
  PF2(pa0, pb0, pa1, pb1, ar0, ar1, 64 + kofs);

  __syncthreads();  // #1: panel1 ready (also retires last ring reads)

  // =============== PHASE B: H1 = relu(adj@XW1+b1); H1W2 -> regs ===============
#pragma unroll
  for (int i = 0; i < 2; ++i)
#pragma unroll
    for (int j = 0; j < 8; ++j) acc[i][j] = fz;

#pragma unroll
  for (int ks = 0; ks < NKS; ++ks) {
    ROT_BODY(ar0, ar1, NN)
    __builtin_amdgcn_s_setprio(1);
#pragma unroll
    for (int ni = 0; ni < 8; ++ni) {
      bf16x8 bfv = *(const bf16x8*)(panel + ks * 8192 + ni * 1024 + lane * 16);
      acc[0][ni] = __builtin_amdgcn_mfma_f32_16x16x32_bf16(br0, bfv, acc[0][ni], 0, 0, 0);
      acc[1][ni] = __builtin_amdgcn_mfma_f32_16x16x32_bf16(br1, bfv, acc[1][ni], 0, 0, 0);
    }
    __builtin_amdgcn_s_setprio(0);
  }

  // epilogue: bias+relu+mask, gh1 partials, per-wave transpose, GEMM2 -> packed ph
  float b1v[8];
#pragma unroll
  for (int ni = 0; ni < 8; ++ni) b1v[ni] = b1[ni * 16 + l15];
  float sgh[8];
#pragma unroll
  for (int ni = 0; ni < 8; ++ni) sgh[ni] = 0.f;
  unsigned ph[2][8][2];
#pragma unroll
  for (int t = 0; t < 2; ++t) {
#pragma unroll
    for (int ni = 0; ni < 8; ++ni) {
      const float bias = b1v[ni];
      float ssum = 0.f;
#pragma unroll
      for (int r = 0; r < 4; ++r) {
        const int orow = wid * 32 + t * 16 + lg * 4 + r;
        float h = acc[t][ni][r] + bias;
        h = h > 0.f ? h : 0.f;
        if (orow >= NN) h = 0.f;
        h1s[(lg * 4 + r) * 136 + ni * 16 + l15] = f2bf(h);
        ssum += h;
      }
      ssum += __shfl_xor(ssum, 16);
      ssum += __shfl_xor(ssum, 32);
      sgh[ni] += ssum;                               // meaningful on lg==0 lanes
    }
    f32x4 acc2[8];
#pragma unroll
    for (int j = 0; j < 8; ++j) acc2[j] = fz;
#pragma unroll
    for (int ks2 = 0; ks2 < 4; ++ks2) {
      bf16x8 a2 = *(const bf16x8*)&h1s[l15 * 136 + ks2 * 32 + lg * 8];
      __builtin_amdgcn_s_setprio(1);
#pragma unroll
      for (int ni = 0; ni < 8; ++ni) {
        bf16x8 b2f = *(const bf16x8*)(W2T + ks2 * 4096 + ni * 512 + lane * 8);
        acc2[ni] = __builtin_amdgcn_mfma_f32_16x16x32_bf16(a2, b2f, acc2[ni], 0, 0, 0);
      }
      __builtin_amdgcn_s_setprio(0);
    }
#pragma unroll
    for (int ni = 0; ni < 8; ++ni) {
      ph[t][ni][0] = (unsigned)f2bf(acc2[ni][0]) | ((unsigned)f2bf(acc2[ni][1]) << 16);
      ph[t][ni][1] = (unsigned)f2bf(acc2[ni][2]) | ((unsigned)f2bf(acc2[ni][3]) << 16);
    }
  }
  if (lg == 0) {
#pragma unroll
    for (int ni = 0; ni < 8; ++ni) ghl[wid * 128 + ni * 16 + l15] = sgh[ni];
  }
  __syncthreads();  // #2: panel1 fully consumed, ghl1 ready

  // phase-C head-start: same adj rows; loads land by barrier #3 exit
  PF2(ea0, eb0, ea1, eb1, ar0, ar1, kofs);
  PF2(oa0, ob0, oa1, ob1, ar0, ar1, 32 + kofs);
  PF2(pa0, pb0, pa1, pb1, ar0, ar1, 64 + kofs);

  // panel2 overwrite: value (n=wid*32+t*16+lg*4+r, j=ni*16+l15), b64 packed (r=0..3)
  {
    char* pw2 = panel + wid * 8192 + (lg >> 1) * 256 + l15 * 16 + (lg & 1) * 8;
#pragma unroll
    for (int t = 0; t < 2; ++t)
#pragma unroll
      for (int ni = 0; ni < 8; ++ni)
        *(uint2*)(pw2 + ni * 1024 + t * 512) = make_uint2(ph[t][ni][0], ph[t][ni][1]);
  }
  if (tid < 128) {
    float s = 0.f;
#pragma unroll
    for (int w = 0; w < 12; ++w) s += ghl[w * 128 + tid];
    gh[b * 256 + tid] = s;
  }
  __syncthreads();  // #3: panel2 ready

  // =============== PHASE C: H2 = relu(adj@H1W2+b2) -> out; gh2 ===============
#pragma unroll
  for (int i = 0; i < 2; ++i)
#pragma unroll
    for (int j = 0; j < 8; ++j) acc[i][j] = fz;

#pragma unroll
  for (int ks = 0; ks < NKS; ++ks) {
    ROT_BODY(ar0, ar1, NN)
    __builtin_amdgcn_s_setprio(1);
#pragma unroll
    for (int ni = 0; ni < 8; ++ni) {
      bf16x8 bfv = *(const bf16x8*)(panel + ks * 8192 + ni * 1024 + lane * 16);
      acc[0][ni] = __builtin_amdgcn_mfma_f32_16x16x32_bf16(br0, bfv, acc[0][ni], 0, 0, 0);
      acc[1][ni] = __builtin_amdgcn_mfma_f32_16x16x32_bf16(br1, bfv, acc[1][ni], 0, 0, 0);
    }
    __builtin_amdgcn_s_setprio(0);
  }

  float b2v[8];
#pragma unroll
  for (int ni = 0; ni < 8; ++ni) b2v[ni] = b2[ni * 16 + l15];
  float* outb = out + (size_t)b * NN * NH;
#pragma unroll
  for (int ni = 0; ni < 8; ++ni) sgh[ni] = 0.f;
#pragma unroll
  for (int t = 0; t < 2; ++t) {
#pragma unroll
    for (int ni = 0; ni < 8; ++ni) {
      const float bias = b2v[ni];
      float ssum = 0.f;
#pragma unroll
      for (int r = 0; r < 4; ++r) {
        const int orow = wid * 32 + t * 16 + lg * 4 + r;
        float h = acc[t][ni][r] + bias;
        h = h > 0.f ? h : 0.f;
        if (orow < NN) {
          outb[orow * NH + ni * 16 + l15] = h;
          ssum += h;
        }
      }
      ssum += __shfl_xor(ssum, 16);
      ssum += __shfl_xor(ssum, 32);
      sgh[ni] += ssum;
    }
  }
  if (lg == 0) {
#pragma unroll
    for (int ni = 0; ni < 8; ++ni) ghl[wid * 128 + ni * 16 + l15] = sgh[ni];
  }
  __syncthreads();  // #4
  if (tid < 128) {
    float s = 0.f;
#pragma unroll
    for (int w = 0; w < 12; ++w) s += ghl[w * 128 + tid];
    gh[b * 256 + 128 + tid] = s;
  }
}

extern "C" void kernel_launch(void* const* d_in, const int* in_sizes, int n_in,
                              void* d_out, int out_size, void* d_ws, size_t ws_size,
                              hipStream_t stream) {
  const float* x   = (const float*)d_in[0];
  const float* adj = (const float*)d_in[1];
  const float* W1  = (const float*)d_in[2];
  const float* b1  = (const float*)d_in[3];
  const float* W2  = (const float*)d_in[4];
  const float* b2  = (const float*)d_in[5];
  float* out = (float*)d_out;                       // h2 [256,360,128] then gh [256,256]
  float* gh  = out + (size_t)NB * NN * NH;

  char* ws = (char*)d_ws;
  unsigned short* W1T = (unsigned short*)ws;                // 98,304 B
  unsigned short* W2T = (unsigned short*)(ws + 98304);      // 32,768 B

  const int smem_bytes = 98304 + 52224 + 6144;              // 156,672 B
  hipFuncSetAttribute((const void*)k_fused, hipFuncAttributeMaxDynamicSharedMemorySize,
                      smem_bytes);

  k_prep <<<256, 256, 0, stream>>>(W1, W2, W1T, W2T);
  k_fused<<<NB, 768, smem_bytes, stream>>>(x, adj, W1T, W2T, b1, b2, out, gh);
}